// Round 10
// baseline (151.754 us; speedup 1.0000x reference)
//
#include <hip/hip_runtime.h>
#include <math.h>

#define Dm 256
#define Tt 4096

typedef short  s16x8 __attribute__((ext_vector_type(8)));
typedef float  f32x4 __attribute__((ext_vector_type(4)));

__device__ __forceinline__ ushort f2bf(float x) {
    union { float f; unsigned u; } v; v.f = x;
    unsigned r = v.u + 0x7fffu + ((v.u >> 16) & 1u);   // RNE
    return (ushort)(r >> 16);
}

// P_s position: row-major [16][64] ushort with block-XOR swizzle (f(row)=row>>1)
__device__ __forceinline__ int ppos(int row, int key) {
    return row * 64 + (key & 7) + ((((key >> 3) ^ (row >> 1)) & 7) << 3);
}

// ---------------- convert: x(+pos) fp32 -> bf16, 3 matrices ----------------
__global__ __launch_bounds__(256)
void convert_x(const float* __restrict__ xq, const float* __restrict__ xkv,
               const float* __restrict__ pos,
               ushort* __restrict__ A0, ushort* __restrict__ A1, ushort* __restrict__ A2)
{
    const int t = threadIdx.x;
    const int m = blockIdx.y;
    const float* xin = (m == 0) ? xq : xkv;
    ushort* out = (m == 0) ? A0 : (m == 1) ? A1 : A2;
    const int token = blockIdx.x * 32 + (t >> 3);
    const int c0 = (t & 7) * 32;
    const float* p = &xin[token * Dm + c0];
    const float* pp = &pos[token * Dm + c0];
    #pragma unroll
    for (int i = 0; i < 4; ++i) {
        float4 fa = *(const float4*)&p[i * 8];
        float4 fb = *(const float4*)&p[i * 8 + 4];
        if (m < 2) {
            float4 pa = *(const float4*)&pp[i * 8], pb = *(const float4*)&pp[i * 8 + 4];
            fa.x += pa.x; fa.y += pa.y; fa.z += pa.z; fa.w += pa.w;
            fb.x += pb.x; fb.y += pb.y; fb.z += pb.z; fb.w += pb.w;
        }
        s16x8 v8;
        v8[0] = (short)f2bf(fa.x); v8[1] = (short)f2bf(fa.y);
        v8[2] = (short)f2bf(fa.z); v8[3] = (short)f2bf(fa.w);
        v8[4] = (short)f2bf(fb.x); v8[5] = (short)f2bf(fb.y);
        v8[6] = (short)f2bf(fb.z); v8[7] = (short)f2bf(fb.w);
        *(s16x8*)&out[token * Dm + c0 + i * 8] = v8;
    }
}

// ---------------- prep: W[k][c] fp32 -> Wt[c][k] bf16, 4 matrices ----------------
__global__ __launch_bounds__(256)
void prep_w(const float* __restrict__ Wq, const float* __restrict__ Wk,
            const float* __restrict__ Wv, const float* __restrict__ Wo,
            ushort* __restrict__ Wt)
{
    __shared__ float T[64][65];
    const int tid = threadIdx.x;
    const int m = blockIdx.y;
    const int i = blockIdx.x >> 2, j = blockIdx.x & 3;
    const float* W = (m == 0) ? Wq : (m == 1) ? Wk : (m == 2) ? Wv : Wo;

    #pragma unroll
    for (int s = 0; s < 4; ++s) {
        int idx = s * 256 + tid;
        int r = idx >> 4, c4 = (idx & 15) << 2;
        float4 f = *(const float4*)&W[(i * 64 + r) * Dm + j * 64 + c4];
        T[c4 + 0][r] = f.x; T[c4 + 1][r] = f.y;
        T[c4 + 2][r] = f.z; T[c4 + 3][r] = f.w;
    }
    __syncthreads();
    #pragma unroll
    for (int s = 0; s < 2; ++s) {
        int idx = s * 256 + tid;
        int cr = idx >> 3, k8 = (idx & 7) << 3;
        s16x8 v8;
        #pragma unroll
        for (int jj = 0; jj < 8; ++jj) v8[jj] = (short)f2bf(T[cr][k8 + jj]);
        *(s16x8*)&Wt[m * 65536 + (j * 64 + cr) * Dm + i * 64 + k8] = v8;
    }
}

// ---------------- QKV projection GEMM: LDS-free, barrier-free ----------------
// grid (32, 4, 3), block 256. Block: 128 tokens x 64 cols; wave: 2 x (16tok x 64col).
// All fragments are contiguous 16B lines in L2-resident buffers.
__global__ __launch_bounds__(256)
void proj_gemm(const ushort* __restrict__ A0, const ushort* __restrict__ A1,
               const ushort* __restrict__ A2, const ushort* __restrict__ Wt,
               const float* __restrict__ bq, const float* __restrict__ bk,
               const float* __restrict__ bv,
               ushort* __restrict__ qo, ushort* __restrict__ ko, ushort* __restrict__ vo)
{
    const int tid = threadIdx.x;
    const int lane = tid & 63, g = lane >> 4, myrow = lane & 15, w = tid >> 6;
    const int t0 = blockIdx.x * 128;
    const int c0 = blockIdx.y * 64;
    const int m  = blockIdx.z;
    const ushort* Ab = (m == 0) ? A0 : (m == 1) ? A1 : A2;
    const ushort* WT = Wt + m * 65536;
    const float* bias = (m == 0) ? bq : (m == 1) ? bk : bv;
    ushort* out = (m == 0) ? qo : (m == 1) ? ko : vo;

    const int rowA0 = t0 + w * 16 + myrow;
    const int rowA1 = rowA0 + 64;

    f32x4 acc[2][4] = {};
    #pragma unroll 2
    for (int kk = 0; kk < 8; ++kk) {
        const int kofs = kk * 32 + g * 8;
        s16x8 a0 = *(const s16x8*)&Ab[rowA0 * Dm + kofs];
        s16x8 a1 = *(const s16x8*)&Ab[rowA1 * Dm + kofs];
        #pragma unroll
        for (int ct = 0; ct < 4; ++ct) {
            s16x8 b = *(const s16x8*)&WT[(c0 + ct * 16 + myrow) * Dm + kofs];
            acc[0][ct] = __builtin_amdgcn_mfma_f32_16x16x32_bf16(a0, b, acc[0][ct], 0, 0, 0);
            acc[1][ct] = __builtin_amdgcn_mfma_f32_16x16x32_bf16(a1, b, acc[1][ct], 0, 0, 0);
        }
    }
    const float qsc = 0.17677669529663687f;   // 1/sqrt(32) folded into q
    #pragma unroll
    for (int ct = 0; ct < 4; ++ct) {
        int col = c0 + ct * 16 + myrow;
        float bval = bias[col];
        #pragma unroll
        for (int st = 0; st < 2; ++st) {
            #pragma unroll
            for (int r = 0; r < 4; ++r) {
                int tok = t0 + st * 64 + w * 16 + 4 * g + r;
                float vv = acc[st][ct][r] + bval;
                if (m == 0) vv *= qsc;
                out[tok * Dm + col] = f2bf(vv);
            }
        }
    }
}

// ---------------- v [T][D] -> vT [D][T] transpose (bf16) ----------------
__global__ __launch_bounds__(256)
void transp_v(const ushort* __restrict__ v, ushort* __restrict__ vT)
{
    __shared__ __align__(16) ushort T_s[64 * 72];
    const int tid = threadIdx.x;
    const int t0 = blockIdx.x * 64;
    const int c0 = blockIdx.y * 64;
    #pragma unroll
    for (int s = 0; s < 2; ++s) {
        int idx = s * 256 + tid;
        int row = idx >> 3, c8 = (idx & 7) << 3;
        s16x8 d = *(const s16x8*)&v[(t0 + row) * Dm + c0 + c8];
        #pragma unroll
        for (int j = 0; j < 8; ++j) {
            int c = c8 + j;
            T_s[c * 72 + (row ^ ((c & 7) << 3))] = (ushort)d[j];
        }
    }
    __syncthreads();
    #pragma unroll
    for (int s = 0; s < 2; ++s) {
        int idx = s * 256 + tid;
        int c = idx >> 3, k8 = (idx & 7) << 3;
        s16x8 d = *(const s16x8*)&T_s[c * 72 + (k8 ^ ((c & 7) << 3))];
        *(s16x8*)&vT[(c0 + c) * Tt + t0 + k8] = d;
    }
}

// ---------------- flash attention: direct-global K/V, P via LDS, NO fences ----------------
// grid 1024 (128 q-tiles x 8 heads), block 256; 4 waves split K 4-ways; combine at end.
// Wave-private P_s: DS ops of one wave are in-order and the compiler cannot reorder
// aliasing same-buffer LDS accesses, so no explicit waitcnt/sched fences are needed —
// letting the compiler software-pipeline QK / softmax / PV across phases.
__global__ __launch_bounds__(256)
void attn4(const ushort* __restrict__ q, const ushort* __restrict__ kb,
           const ushort* __restrict__ vT, ushort* __restrict__ o)
{
    __shared__ __align__(16) ushort P_s[4][16 * 64];   // per-wave swizzled P (8 KB)
    __shared__ float cmb[96 * 36];                     // combine buffer (13.8 KB)
    const int tid = threadIdx.x;
    const int lane = tid & 63, g = lane >> 4, myrow = lane & 15, w = tid >> 6;
    const int h = blockIdx.x & 7, qt = blockIdx.x >> 3;

    int off, L;
    if (qt < 32)      { off = 0;    L = 1024; }
    else if (qt < 48) { off = 1024; L = 512;  }
    else if (qt < 96) { off = 1536; L = 1536; }
    else              { off = 3072; L = 1024; }
    const int qrow0 = qt * 32;
    const int Lw = L >> 2;
    const int kbeg = off + w * Lw;
    const int ntk = Lw >> 6;

    s16x8 qf[2];
    qf[0] = *(const s16x8*)&q[(qrow0 + myrow) * Dm + h * 32 + g * 8];
    qf[1] = *(const s16x8*)&q[(qrow0 + 16 + myrow) * Dm + h * 32 + g * 8];

    f32x4 aO[2][2] = {};
    float mr[2][4], lr[2][4];
    #pragma unroll
    for (int s = 0; s < 2; ++s)
        #pragma unroll
        for (int r = 0; r < 4; ++r) { mr[s][r] = -INFINITY; lr[s][r] = 0.f; }

    for (int t = 0; t < ntk; ++t) {
        const int kt0 = kbeg + t * 64;
        // K fragments: B-op of QK^T (col=key=myrow, k=dh=8g+j); s-phase invariant.
        s16x8 kf[4];
        #pragma unroll
        for (int kt = 0; kt < 4; ++kt)
            kf[kt] = *(const s16x8*)&kb[(kt0 + kt * 16 + myrow) * Dm + h * 32 + g * 8];
        // V fragments: B-op of PV (col=dh=myrow(+16), k=key=32kk+8g+j); s-phase invariant.
        s16x8 vfa[2], vfb[2];
        #pragma unroll
        for (int kk = 0; kk < 2; ++kk) {
            vfa[kk] = *(const s16x8*)&vT[(h * 32 + myrow) * Tt + kt0 + kk * 32 + g * 8];
            vfb[kk] = *(const s16x8*)&vT[(h * 32 + 16 + myrow) * Tt + kt0 + kk * 32 + g * 8];
        }

        #pragma unroll
        for (int s = 0; s < 2; ++s) {
            const f32x4 zero = {};
            f32x4 s4[4];
            #pragma unroll
            for (int kt = 0; kt < 4; ++kt)
                s4[kt] = __builtin_amdgcn_mfma_f32_16x16x32_bf16(qf[s], kf[kt], zero, 0, 0, 0);

            float mt[4], sc[4], ps[4];
            #pragma unroll
            for (int r = 0; r < 4; ++r) {
                float a = fmaxf(fmaxf(s4[0][r], s4[1][r]), fmaxf(s4[2][r], s4[3][r]));
                a = fmaxf(a, __shfl_xor(a, 1));
                a = fmaxf(a, __shfl_xor(a, 2));
                a = fmaxf(a, __shfl_xor(a, 4));
                a = fmaxf(a, __shfl_xor(a, 8));
                mt[r] = a;
            }
            #pragma unroll
            for (int r = 0; r < 4; ++r) {
                float mn = fmaxf(mr[s][r], mt[r]);
                sc[r] = __expf(mr[s][r] - mn);
                mr[s][r] = mn;
                ps[r] = 0.f;
            }
            #pragma unroll
            for (int kt = 0; kt < 4; ++kt) {
                #pragma unroll
                for (int r = 0; r < 4; ++r) {
                    float p = __expf(s4[kt][r] - mr[s][r]);
                    ps[r] += p;
                    P_s[w][ppos(4 * g + r, 16 * kt + myrow)] = f2bf(p);
                }
            }
            #pragma unroll
            for (int r = 0; r < 4; ++r) {
                float sps = ps[r];
                sps += __shfl_xor(sps, 1);
                sps += __shfl_xor(sps, 2);
                sps += __shfl_xor(sps, 4);
                sps += __shfl_xor(sps, 8);
                lr[s][r] = lr[s][r] * sc[r] + sps;
                aO[s][0][r] *= sc[r];
                aO[s][1][r] *= sc[r];
            }
            #pragma unroll
            for (int kk = 0; kk < 2; ++kk) {
                s16x8 ap = *(const s16x8*)&P_s[w][ppos(myrow, (g + 4 * kk) * 8)];
                aO[s][0] = __builtin_amdgcn_mfma_f32_16x16x32_bf16(ap, vfa[kk], aO[s][0], 0, 0, 0);
                aO[s][1] = __builtin_amdgcn_mfma_f32_16x16x32_bf16(ap, vfb[kk], aO[s][1], 0, 0, 0);
            }
        }
    }

    // cross-wave combine: waves 1-3 publish partials, wave 0 merges + writes.
    __syncthreads();
    if (w > 0) {
        #pragma unroll
        for (int s = 0; s < 2; ++s)
            #pragma unroll
            for (int r = 0; r < 4; ++r) {
                int row = (w - 1) * 32 + s * 16 + 4 * g + r;
                cmb[row * 36 + myrow]      = aO[s][0][r];
                cmb[row * 36 + 16 + myrow] = aO[s][1][r];
                if (myrow == 0) { cmb[row * 36 + 32] = mr[s][r]; cmb[row * 36 + 33] = lr[s][r]; }
            }
    }
    __syncthreads();
    if (w == 0) {
        #pragma unroll
        for (int s = 0; s < 2; ++s) {
            #pragma unroll
            for (int r = 0; r < 4; ++r) {
                #pragma unroll
                for (int ww = 0; ww < 3; ++ww) {
                    int row = ww * 32 + s * 16 + 4 * g + r;
                    float m2 = cmb[row * 36 + 32], l2 = cmb[row * 36 + 33];
                    float mn = fmaxf(mr[s][r], m2);
                    float a1 = __expf(mr[s][r] - mn), a2 = __expf(m2 - mn);
                    mr[s][r] = mn;
                    lr[s][r] = lr[s][r] * a1 + l2 * a2;
                    aO[s][0][r] = aO[s][0][r] * a1 + cmb[row * 36 + myrow] * a2;
                    aO[s][1][r] = aO[s][1][r] * a1 + cmb[row * 36 + 16 + myrow] * a2;
                }
                float inv = 1.0f / lr[s][r];
                int orow = (qrow0 + s * 16 + 4 * g + r) * Dm + h * 32;
                o[orow + myrow]      = f2bf(aO[s][0][r] * inv);
                o[orow + 16 + myrow] = f2bf(aO[s][1][r] * inv);
            }
        }
    }
}

// ---------------- output projection: LDS-free, barrier-free ----------------
// grid (32, 4), block 256. Block: 128 tokens x 64 cols, fp32 out.
__global__ __launch_bounds__(256)
void oproj_mfma(const ushort* __restrict__ A, const ushort* __restrict__ Wt3,
                const float* __restrict__ bo, float* __restrict__ out)
{
    const int tid = threadIdx.x;
    const int lane = tid & 63, g = lane >> 4, myrow = lane & 15, w = tid >> 6;
    const int t0 = blockIdx.x * 128;
    const int c0 = blockIdx.y * 64;

    const int rowA0 = t0 + w * 16 + myrow;
    const int rowA1 = rowA0 + 64;

    f32x4 acc[2][4] = {};
    #pragma unroll 2
    for (int kk = 0; kk < 8; ++kk) {
        const int kofs = kk * 32 + g * 8;
        s16x8 a0 = *(const s16x8*)&A[rowA0 * Dm + kofs];
        s16x8 a1 = *(const s16x8*)&A[rowA1 * Dm + kofs];
        #pragma unroll
        for (int ct = 0; ct < 4; ++ct) {
            s16x8 b = *(const s16x8*)&Wt3[(c0 + ct * 16 + myrow) * Dm + kofs];
            acc[0][ct] = __builtin_amdgcn_mfma_f32_16x16x32_bf16(a0, b, acc[0][ct], 0, 0, 0);
            acc[1][ct] = __builtin_amdgcn_mfma_f32_16x16x32_bf16(a1, b, acc[1][ct], 0, 0, 0);
        }
    }
    #pragma unroll
    for (int ct = 0; ct < 4; ++ct) {
        int col = c0 + ct * 16 + myrow;
        float bval = bo[col];
        #pragma unroll
        for (int st = 0; st < 2; ++st) {
            #pragma unroll
            for (int r = 0; r < 4; ++r)
                out[(t0 + st * 64 + w * 16 + 4 * g + r) * Dm + col] = acc[st][ct][r] + bval;
        }
    }
}

extern "C" void kernel_launch(void* const* d_in, const int* in_sizes, int n_in,
                              void* d_out, int out_size, void* d_ws, size_t ws_size,
                              hipStream_t stream) {
    const float* xq  = (const float*)d_in[0];
    const float* xkv = (const float*)d_in[1];
    const float* pos = (const float*)d_in[2];
    const float* Wq  = (const float*)d_in[5];
    const float* bq  = (const float*)d_in[6];
    const float* Wk  = (const float*)d_in[7];
    const float* bk  = (const float*)d_in[8];
    const float* Wv  = (const float*)d_in[9];
    const float* bv  = (const float*)d_in[10];
    const float* Wo  = (const float*)d_in[11];
    const float* bo  = (const float*)d_in[12];

    ushort* Abf = (ushort*)d_ws;           // 3 x [T,D] bf16 (xq+pos, xkv+pos, xkv)
    ushort* qb  = Abf + 3 * Tt * Dm;       // [T,D]
    ushort* kbp = qb + Tt * Dm;            // [T,D]
    ushort* vb  = kbp + Tt * Dm;           // [T,D] row-major v
    ushort* vTt = vb + Tt * Dm;            // [D,T] transposed v
    ushort* ab  = vTt + Tt * Dm;           // attn out [T,D]
    ushort* Wt  = ab + Tt * Dm;            // 4 x [256,256] transposed bf16

    convert_x<<<dim3(Tt / 32, 3), 256, 0, stream>>>(xq, xkv, pos, Abf,
                                                    Abf + Tt * Dm, Abf + 2 * Tt * Dm);
    prep_w<<<dim3(16, 4), 256, 0, stream>>>(Wq, Wk, Wv, Wo, Wt);
    proj_gemm<<<dim3(32, 4, 3), 256, 0, stream>>>(Abf, Abf + Tt * Dm, Abf + 2 * Tt * Dm,
                                                  Wt, bq, bk, bv, qb, kbp, vb);
    transp_v<<<dim3(64, 4), 256, 0, stream>>>(vb, vTt);
    attn4<<<dim3(1024), 256, 0, stream>>>(qb, kbp, vTt, ab);
    oproj_mfma<<<dim3(32, 4), 256, 0, stream>>>(ab, Wt + 3 * 65536, bo, (float*)d_out);
}

// Round 13
// 131.488 us; speedup vs baseline: 1.1541x; 1.1541x over previous
//
#include <hip/hip_runtime.h>
#include <math.h>

#define Dm 256
#define Tt 4096

typedef short  s16x8 __attribute__((ext_vector_type(8)));
typedef float  f32x4 __attribute__((ext_vector_type(4)));

__device__ __forceinline__ ushort f2bf(float x) {
    union { float f; unsigned u; } v; v.f = x;
    unsigned r = v.u + 0x7fffu + ((v.u >> 16) & 1u);   // RNE
    return (ushort)(r >> 16);
}

// ---------------- convert: x(+pos) fp32 -> bf16, 3 matrices ----------------
__global__ __launch_bounds__(256)
void convert_x(const float* __restrict__ xq, const float* __restrict__ xkv,
               const float* __restrict__ pos,
               ushort* __restrict__ A0, ushort* __restrict__ A1, ushort* __restrict__ A2)
{
    const int t = threadIdx.x;
    const int m = blockIdx.y;
    const float* xin = (m == 0) ? xq : xkv;
    ushort* out = (m == 0) ? A0 : (m == 1) ? A1 : A2;
    const int token = blockIdx.x * 32 + (t >> 3);
    const int c0 = (t & 7) * 32;
    const float* p = &xin[token * Dm + c0];
    const float* pp = &pos[token * Dm + c0];
    #pragma unroll
    for (int i = 0; i < 4; ++i) {
        float4 fa = *(const float4*)&p[i * 8];
        float4 fb = *(const float4*)&p[i * 8 + 4];
        if (m < 2) {
            float4 pa = *(const float4*)&pp[i * 8], pb = *(const float4*)&pp[i * 8 + 4];
            fa.x += pa.x; fa.y += pa.y; fa.z += pa.z; fa.w += pa.w;
            fb.x += pb.x; fb.y += pb.y; fb.z += pb.z; fb.w += pb.w;
        }
        s16x8 v8;
        v8[0] = (short)f2bf(fa.x); v8[1] = (short)f2bf(fa.y);
        v8[2] = (short)f2bf(fa.z); v8[3] = (short)f2bf(fa.w);
        v8[4] = (short)f2bf(fb.x); v8[5] = (short)f2bf(fb.y);
        v8[6] = (short)f2bf(fb.z); v8[7] = (short)f2bf(fb.w);
        *(s16x8*)&out[token * Dm + c0 + i * 8] = v8;
    }
}

// ---------------- prep: W[k][c] fp32 -> Wt[c][k] bf16, 4 matrices ----------------
__global__ __launch_bounds__(256)
void prep_w(const float* __restrict__ Wq, const float* __restrict__ Wk,
            const float* __restrict__ Wv, const float* __restrict__ Wo,
            ushort* __restrict__ Wt)
{
    __shared__ float T[64][65];
    const int tid = threadIdx.x;
    const int m = blockIdx.y;
    const int i = blockIdx.x >> 2, j = blockIdx.x & 3;
    const float* W = (m == 0) ? Wq : (m == 1) ? Wk : (m == 2) ? Wv : Wo;

    #pragma unroll
    for (int s = 0; s < 4; ++s) {
        int idx = s * 256 + tid;
        int r = idx >> 4, c4 = (idx & 15) << 2;
        float4 f = *(const float4*)&W[(i * 64 + r) * Dm + j * 64 + c4];
        T[c4 + 0][r] = f.x; T[c4 + 1][r] = f.y;
        T[c4 + 2][r] = f.z; T[c4 + 3][r] = f.w;
    }
    __syncthreads();
    #pragma unroll
    for (int s = 0; s < 2; ++s) {
        int idx = s * 256 + tid;
        int cr = idx >> 3, k8 = (idx & 7) << 3;
        s16x8 v8;
        #pragma unroll
        for (int jj = 0; jj < 8; ++jj) v8[jj] = (short)f2bf(T[cr][k8 + jj]);
        *(s16x8*)&Wt[m * 65536 + (j * 64 + cr) * Dm + i * 64 + k8] = v8;
    }
}

// ---------------- QKV projection GEMM (R9 LDS version) ----------------
__global__ __launch_bounds__(256)
void proj_gemm(const ushort* __restrict__ A0, const ushort* __restrict__ A1,
               const ushort* __restrict__ A2, const ushort* __restrict__ Wt,
               const float* __restrict__ bq, const float* __restrict__ bk,
               const float* __restrict__ bv,
               ushort* __restrict__ qo, ushort* __restrict__ ko, ushort* __restrict__ vo)
{
    __shared__ __align__(16) ushort A_s[64 * 64];
    __shared__ __align__(16) ushort B_s[64 * 64];
    const int tid = threadIdx.x;
    const int lane = tid & 63, g = lane >> 4, myrow = lane & 15, w = tid >> 6;
    const int t0 = blockIdx.x * 64;
    const int c0 = blockIdx.y * 64;
    const int m  = blockIdx.z;
    const ushort* Ab = (m == 0) ? A0 : (m == 1) ? A1 : A2;
    const ushort* WT = Wt + m * 65536;
    const float* bias = (m == 0) ? bq : (m == 1) ? bk : bv;
    ushort* out = (m == 0) ? qo : (m == 1) ? ko : vo;

    f32x4 acc[4] = {};
    for (int ks = 0; ks < 4; ++ks) {
        const int k0 = ks * 64;
        #pragma unroll
        for (int s = 0; s < 2; ++s) {
            int idx = s * 256 + tid;
            int r = idx >> 3, c = idx & 7;
            *(s16x8*)&A_s[r * 64 + ((c ^ (r & 7)) << 3)] =
                *(const s16x8*)&Ab[(t0 + r) * Dm + k0 + c * 8];
            *(s16x8*)&B_s[r * 64 + ((c ^ (r & 7)) << 3)] =
                *(const s16x8*)&WT[(c0 + r) * Dm + k0 + c * 8];
        }
        __syncthreads();
        const int arow = w * 16 + myrow;
        #pragma unroll
        for (int kk = 0; kk < 2; ++kk) {
            s16x8 a = *(s16x8*)&A_s[arow * 64 + (((g + 4 * kk) ^ (arow & 7)) << 3)];
            #pragma unroll
            for (int ct = 0; ct < 4; ++ct) {
                int brow = ct * 16 + myrow;
                s16x8 b = *(s16x8*)&B_s[brow * 64 + (((g + 4 * kk) ^ (brow & 7)) << 3)];
                acc[ct] = __builtin_amdgcn_mfma_f32_16x16x32_bf16(a, b, acc[ct], 0, 0, 0);
            }
        }
        __syncthreads();
    }
    // q pre-scaled by 1/sqrt(32) * log2(e)  (attention works in exp2 domain)
    const float qsc = 0.25503482f;
    #pragma unroll
    for (int ct = 0; ct < 4; ++ct) {
        int col = c0 + ct * 16 + myrow;
        float bval = bias[col];
        #pragma unroll
        for (int r = 0; r < 4; ++r) {
            int tok = t0 + w * 16 + 4 * g + r;
            float vv = acc[ct][r] + bval;
            if (m == 0) vv *= qsc;
            out[tok * Dm + col] = f2bf(vv);
        }
    }
}

// ---------------- v [T][D] -> vT [D][T] transpose (bf16) ----------------
__global__ __launch_bounds__(256)
void transp_v(const ushort* __restrict__ v, ushort* __restrict__ vT)
{
    __shared__ __align__(16) ushort T_s[64 * 72];
    const int tid = threadIdx.x;
    const int t0 = blockIdx.x * 64;
    const int c0 = blockIdx.y * 64;
    #pragma unroll
    for (int s = 0; s < 2; ++s) {
        int idx = s * 256 + tid;
        int row = idx >> 3, c8 = (idx & 7) << 3;
        s16x8 d = *(const s16x8*)&v[(t0 + row) * Dm + c0 + c8];
        #pragma unroll
        for (int j = 0; j < 8; ++j) {
            int c = c8 + j;
            T_s[c * 72 + (row ^ ((c & 7) << 3))] = (ushort)d[j];
        }
    }
    __syncthreads();
    #pragma unroll
    for (int s = 0; s < 2; ++s) {
        int idx = s * 256 + tid;
        int c = idx >> 3, k8 = (idx & 7) << 3;
        s16x8 d = *(const s16x8*)&T_s[c * 72 + (k8 ^ ((c & 7) << 3))];
        *(s16x8*)&vT[(c0 + c) * Tt + t0 + k8] = d;
    }
}

// ---------------- flash attention: fully swapped (S^T, O^T), register-only P ----------------
// grid 1024 (128 q-tiles x 8 heads), block 256; 4 waves split K; no LDS in main loop.
// S^T = mfma(K,Q): lane holds 16 scores of q-row (lane&15).  Softmax lane-local.
// P^T reaches PV's B-fragment via shuffles. NOTE: dest lane (g,myrow) needs source's
// pk[2kk + (g_dst>>1)]; one source serves two dests with different kt, so BOTH kt
// candidates are shuffled and the select happens on the destination (R11 bugfix).
// O^T = mfma(V^T, P^T): rescale/divide lane-local.
__global__ __launch_bounds__(256)
void attn5(const ushort* __restrict__ q, const ushort* __restrict__ kb,
           const ushort* __restrict__ vT, ushort* __restrict__ o)
{
    __shared__ __align__(16) float cmb[96 * 36];       // combine buffer (13.8 KB)
    const int tid = threadIdx.x;
    const int lane = tid & 63, g = lane >> 4, myrow = lane & 15, w = tid >> 6;
    const int h = blockIdx.x & 7, qt = blockIdx.x >> 3;

    int off, L;
    if (qt < 32)      { off = 0;    L = 1024; }
    else if (qt < 48) { off = 1024; L = 512;  }
    else if (qt < 96) { off = 1536; L = 1536; }
    else              { off = 3072; L = 1024; }
    const int qrow0 = qt * 32;
    const int Lw = L >> 2;
    const int kbeg = off + w * Lw;
    const int ntk = Lw >> 6;

    // Q as B-fragment (col=q=myrow, k=dh=8g+j); pre-scaled by log2e/sqrt(dh)
    s16x8 qf[2];
    qf[0] = *(const s16x8*)&q[(qrow0 + myrow) * Dm + h * 32 + g * 8];
    qf[1] = *(const s16x8*)&q[(qrow0 + 16 + myrow) * Dm + h * 32 + g * 8];

    f32x4 aT[2][2] = {};                   // O^T accum: [s][dh-half]; lane: q=myrow, dh=16*half+4g+r
    float mr[2] = {-INFINITY, -INFINITY};
    float lr[2] = {0.f, 0.f};

    for (int t = 0; t < ntk; ++t) {
        const int kt0 = kbeg + t * 64;
        // K as A-fragment (row=key=myrow, k=dh=8g+j)
        s16x8 kf[4];
        #pragma unroll
        for (int kt = 0; kt < 4; ++kt)
            kf[kt] = *(const s16x8*)&kb[(kt0 + kt * 16 + myrow) * Dm + h * 32 + g * 8];
        // V^T as A-fragment (row=dh=myrow(+16), k=key=32kk+8g+j)
        s16x8 vfa[2], vfb[2];
        #pragma unroll
        for (int kk = 0; kk < 2; ++kk) {
            vfa[kk] = *(const s16x8*)&vT[(h * 32 + myrow) * Tt + kt0 + kk * 32 + g * 8];
            vfb[kk] = *(const s16x8*)&vT[(h * 32 + 16 + myrow) * Tt + kt0 + kk * 32 + g * 8];
        }

        #pragma unroll
        for (int s = 0; s < 2; ++s) {
            const f32x4 zero = {};
            f32x4 sc4[4];                  // S^T: lane q=myrow, key=16kt+4g+r
            #pragma unroll
            for (int kt = 0; kt < 4; ++kt)
                sc4[kt] = __builtin_amdgcn_mfma_f32_16x16x32_bf16(kf[kt], qf[s], zero, 0, 0, 0);

            // row max: 16 in-lane + cross-g (lanes 16g+myrow hold same q)
            float mx0 = fmaxf(fmaxf(sc4[0][0], sc4[0][1]), fmaxf(sc4[0][2], sc4[0][3]));
            float mx1 = fmaxf(fmaxf(sc4[1][0], sc4[1][1]), fmaxf(sc4[1][2], sc4[1][3]));
            float mx2 = fmaxf(fmaxf(sc4[2][0], sc4[2][1]), fmaxf(sc4[2][2], sc4[2][3]));
            float mx3 = fmaxf(fmaxf(sc4[3][0], sc4[3][1]), fmaxf(sc4[3][2], sc4[3][3]));
            float mx = fmaxf(fmaxf(mx0, mx1), fmaxf(mx2, mx3));
            mx = fmaxf(mx, __shfl_xor(mx, 16));
            mx = fmaxf(mx, __shfl_xor(mx, 32));
            float mn = fmaxf(mr[s], mx);
            float scl = exp2f(mr[s] - mn);      // exp2(-inf)=0 first tile
            mr[s] = mn;

            float p[4][4];
            float psum = 0.f;
            #pragma unroll
            for (int kt = 0; kt < 4; ++kt)
                #pragma unroll
                for (int r = 0; r < 4; ++r) {
                    p[kt][r] = exp2f(sc4[kt][r] - mn);
                    psum += p[kt][r];
                }
            psum += __shfl_xor(psum, 16);
            psum += __shfl_xor(psum, 32);
            lr[s] = lr[s] * scl + psum;
            #pragma unroll
            for (int r = 0; r < 4; ++r) { aT[s][0][r] *= scl; aT[s][1][r] *= scl; }

            // pack P^T pairs: pk[kt][i] = bf16(key 16kt+4g+2i) | bf16(+2i+1)<<16
            unsigned pk[4][2];
            #pragma unroll
            for (int kt = 0; kt < 4; ++kt) {
                pk[kt][0] = (unsigned)f2bf(p[kt][0]) | ((unsigned)f2bf(p[kt][1]) << 16);
                pk[kt][1] = (unsigned)f2bf(p[kt][2]) | ((unsigned)f2bf(p[kt][3]) << 16);
            }

            // exchange to B-fragment (col=q=myrow, k=key=32kk+8g+j) + PV.
            // Shuffle BOTH kt candidates; select with the DEST lane's (g>>1).
            const int lA = (g & 1) * 32 + myrow;     // src for keys 32kk+8g+0..3
            const int lB = lA + 16;                  // src for keys 32kk+8g+4..7
            const bool hi = (g >> 1) != 0;
            #pragma unroll
            for (int kk = 0; kk < 2; ++kk) {
                int a0 = __shfl((int)pk[2 * kk][0],     lA, 64);
                int a1 = __shfl((int)pk[2 * kk][1],     lA, 64);
                int a2 = __shfl((int)pk[2 * kk][0],     lB, 64);
                int a3 = __shfl((int)pk[2 * kk][1],     lB, 64);
                int b0 = __shfl((int)pk[2 * kk + 1][0], lA, 64);
                int b1 = __shfl((int)pk[2 * kk + 1][1], lA, 64);
                int b2 = __shfl((int)pk[2 * kk + 1][0], lB, 64);
                int b3 = __shfl((int)pk[2 * kk + 1][1], lB, 64);
                union { int i[4]; s16x8 v; } pb;
                pb.i[0] = hi ? b0 : a0;
                pb.i[1] = hi ? b1 : a1;
                pb.i[2] = hi ? b2 : a2;
                pb.i[3] = hi ? b3 : a3;
                aT[s][0] = __builtin_amdgcn_mfma_f32_16x16x32_bf16(vfa[kk], pb.v, aT[s][0], 0, 0, 0);
                aT[s][1] = __builtin_amdgcn_mfma_f32_16x16x32_bf16(vfb[kk], pb.v, aT[s][1], 0, 0, 0);
            }
        }
    }

    // cross-wave combine: waves 1-3 publish O^T partials + (m,l); wave 0 merges + writes.
    __syncthreads();
    if (w > 0) {
        #pragma unroll
        for (int s = 0; s < 2; ++s) {
            int row = (w - 1) * 32 + 16 * s + myrow;
            *(float4*)&cmb[row * 36 + 4 * g]      = (float4){aT[s][0][0], aT[s][0][1], aT[s][0][2], aT[s][0][3]};
            *(float4*)&cmb[row * 36 + 16 + 4 * g] = (float4){aT[s][1][0], aT[s][1][1], aT[s][1][2], aT[s][1][3]};
            if (g == 0) { cmb[row * 36 + 32] = mr[s]; cmb[row * 36 + 33] = lr[s]; }
        }
    }
    __syncthreads();
    if (w == 0) {
        #pragma unroll
        for (int s = 0; s < 2; ++s) {
            #pragma unroll
            for (int ww = 0; ww < 3; ++ww) {
                int row = ww * 32 + 16 * s + myrow;
                float m2 = cmb[row * 36 + 32], l2 = cmb[row * 36 + 33];
                float mn = fmaxf(mr[s], m2);
                float a1 = exp2f(mr[s] - mn), a2 = exp2f(m2 - mn);
                mr[s] = mn;
                lr[s] = lr[s] * a1 + l2 * a2;
                float4 c0_ = *(float4*)&cmb[row * 36 + 4 * g];
                float4 c1_ = *(float4*)&cmb[row * 36 + 16 + 4 * g];
                aT[s][0][0] = aT[s][0][0] * a1 + c0_.x * a2;
                aT[s][0][1] = aT[s][0][1] * a1 + c0_.y * a2;
                aT[s][0][2] = aT[s][0][2] * a1 + c0_.z * a2;
                aT[s][0][3] = aT[s][0][3] * a1 + c0_.w * a2;
                aT[s][1][0] = aT[s][1][0] * a1 + c1_.x * a2;
                aT[s][1][1] = aT[s][1][1] * a1 + c1_.y * a2;
                aT[s][1][2] = aT[s][1][2] * a1 + c1_.z * a2;
                aT[s][1][3] = aT[s][1][3] * a1 + c1_.w * a2;
            }
            float inv = 1.0f / lr[s];
            int base = (qrow0 + 16 * s + myrow) * Dm + h * 32;
            #pragma unroll
            for (int half = 0; half < 2; ++half) {
                ushort4 r4;
                r4.x = f2bf(aT[s][half][0] * inv);
                r4.y = f2bf(aT[s][half][1] * inv);
                r4.z = f2bf(aT[s][half][2] * inv);
                r4.w = f2bf(aT[s][half][3] * inv);
                *(ushort4*)&o[base + 16 * half + 4 * g] = r4;
            }
        }
    }
}

// ---------------- output projection (R9 LDS version) ----------------
__global__ __launch_bounds__(256)
void oproj_mfma(const ushort* __restrict__ A, const ushort* __restrict__ Wt3,
                const float* __restrict__ bo, float* __restrict__ out)
{
    __shared__ __align__(16) ushort A_s[32 * 64];
    __shared__ __align__(16) ushort B_s[64 * 64];
    const int tid = threadIdx.x;
    const int lane = tid & 63, g = lane >> 4, myrow = lane & 15, w = tid >> 6;
    const int sh = w >> 1, ch = w & 1;
    const int t0 = blockIdx.x * 32;
    const int c0 = blockIdx.y * 64;

    f32x4 acc[2] = {};
    for (int ks = 0; ks < 4; ++ks) {
        const int k0 = ks * 64;
        {
            int r = tid >> 3, c = tid & 7;
            *(s16x8*)&A_s[r * 64 + ((c ^ (r & 7)) << 3)] =
                *(const s16x8*)&A[(t0 + r) * Dm + k0 + c * 8];
        }
        #pragma unroll
        for (int s = 0; s < 2; ++s) {
            int idx = s * 256 + tid;
            int r = idx >> 3, c = idx & 7;
            *(s16x8*)&B_s[r * 64 + ((c ^ (r & 7)) << 3)] =
                *(const s16x8*)&Wt3[(c0 + r) * Dm + k0 + c * 8];
        }
        __syncthreads();
        const int arow = sh * 16 + myrow;
        #pragma unroll
        for (int kk = 0; kk < 2; ++kk) {
            s16x8 a = *(s16x8*)&A_s[arow * 64 + (((g + 4 * kk) ^ (arow & 7)) << 3)];
            #pragma unroll
            for (int ct = 0; ct < 2; ++ct) {
                int brow = ch * 32 + ct * 16 + myrow;
                s16x8 b = *(s16x8*)&B_s[brow * 64 + (((g + 4 * kk) ^ (brow & 7)) << 3)];
                acc[ct] = __builtin_amdgcn_mfma_f32_16x16x32_bf16(a, b, acc[ct], 0, 0, 0);
            }
        }
        __syncthreads();
    }
    #pragma unroll
    for (int ct = 0; ct < 2; ++ct) {
        int col = c0 + ch * 32 + ct * 16 + myrow;
        float bval = bo[col];
        #pragma unroll
        for (int r = 0; r < 4; ++r)
            out[(t0 + sh * 16 + 4 * g + r) * Dm + col] = acc[ct][r] + bval;
    }
}

extern "C" void kernel_launch(void* const* d_in, const int* in_sizes, int n_in,
                              void* d_out, int out_size, void* d_ws, size_t ws_size,
                              hipStream_t stream) {
    const float* xq  = (const float*)d_in[0];
    const float* xkv = (const float*)d_in[1];
    const float* pos = (const float*)d_in[2];
    const float* Wq  = (const float*)d_in[5];
    const float* bq  = (const float*)d_in[6];
    const float* Wk  = (const float*)d_in[7];
    const float* bk  = (const float*)d_in[8];
    const float* Wv  = (const float*)d_in[9];
    const float* bv  = (const float*)d_in[10];
    const float* Wo  = (const float*)d_in[11];
    const float* bo  = (const float*)d_in[12];

    ushort* Abf = (ushort*)d_ws;           // 3 x [T,D] bf16 (xq+pos, xkv+pos, xkv)
    ushort* qb  = Abf + 3 * Tt * Dm;       // [T,D]
    ushort* kbp = qb + Tt * Dm;            // [T,D]
    ushort* vb  = kbp + Tt * Dm;           // [T,D] row-major v
    ushort* vTt = vb + Tt * Dm;            // [D,T] transposed v
    ushort* ab  = vTt + Tt * Dm;           // attn out [T,D]
    ushort* Wt  = ab + Tt * Dm;            // 4 x [256,256] transposed bf16

    convert_x<<<dim3(Tt / 32, 3), 256, 0, stream>>>(xq, xkv, pos, Abf,
                                                    Abf + Tt * Dm, Abf + 2 * Tt * Dm);
    prep_w<<<dim3(16, 4), 256, 0, stream>>>(Wq, Wk, Wv, Wo, Wt);
    proj_gemm<<<dim3(64, 4, 3), 256, 0, stream>>>(Abf, Abf + Tt * Dm, Abf + 2 * Tt * Dm,
                                                  Wt, bq, bk, bv, qb, kbp, vb);
    transp_v<<<dim3(64, 4), 256, 0, stream>>>(vb, vTt);
    attn5<<<dim3(1024), 256, 0, stream>>>(qb, kbp, vTt, ab);
    oproj_mfma<<<dim3(128, 4), 256, 0, stream>>>(ab, Wt + 3 * 65536, bo, (float*)d_out);
}